// Round 7
// baseline (269.768 us; speedup 1.0000x reference)
//
#include <hip/hip_runtime.h>
#include <hip/hip_bf16.h>
#include <type_traits>

// SelfAttention fused block, MI355X/gfx950.
// R7: flash — V frags direct from global (L2) kills 1/3 of LDS traffic + V
//     staging; K-only dbuf, vmcnt(10)/vmcnt(2) choreography (never 0); LDS
//     51 KB -> 3 blocks/CU. G6 vt-store via LDS bounce (coalesced 16B).
//     All weight transposes in one launch. 7 launches.

typedef __hip_bfloat16 bf16;
typedef __attribute__((ext_vector_type(8))) short bf16x8;
typedef __attribute__((ext_vector_type(4))) float f32x4;

#define MFMA_BF16(a, b, c) __builtin_amdgcn_mfma_f32_16x16x32_bf16((a), (b), (c), 0, 0, 0)

__device__ __forceinline__ float us2f(unsigned short u) {
  unsigned int v = ((unsigned int)u) << 16;
  return __builtin_bit_cast(float, v);
}

__device__ __forceinline__ unsigned pack_bf16x2(float a, float b) {  // RNE (epilogues)
  union { __hip_bfloat162 h; unsigned u; } cv;
  cv.h = __float22bfloat162_rn(float2{a, b});
  return cv.u;
}

__device__ __forceinline__ unsigned pack_bf16x2_trunc(float a, float b) {  // 1x v_perm
  return __builtin_amdgcn_perm(__builtin_bit_cast(unsigned, b),
                               __builtin_bit_cast(unsigned, a), 0x07060302u);
}

// async global->LDS, 16B per lane; lane i's dest = wave-uniform base + i*16
__device__ __forceinline__ void gl_lds16(const bf16* g, bf16* l) {
  __builtin_amdgcn_global_load_lds(
      (const __attribute__((address_space(1))) void*)g,
      (__attribute__((address_space(3))) void*)l, 16, 0, 0);
}

// ---------------- fused pair of LayerNorms: grid (rows, 2); out scaled by sc ----------------
template <typename TIN>
__global__ __launch_bounds__(256) void ln2_kernel(
    const TIN* __restrict__ in0, const TIN* __restrict__ in1, int stride,
    const float* __restrict__ g0, const float* __restrict__ b0,
    const float* __restrict__ g1, const float* __restrict__ b1,
    bf16* __restrict__ out0, bf16* __restrict__ out1, int D,
    float sc0, float sc1)
{
  const int which = blockIdx.y;
  const TIN* in = which ? in1 : in0;
  const float* gamma = which ? g1 : g0;
  const float* beta = which ? b1 : b0;
  bf16* out = which ? out1 : out0;
  const float sc = which ? sc1 : sc0;
  const int row = blockIdx.x;
  const int t = threadIdx.x;
  float x0, x1, x2, x3;
  if constexpr (std::is_same_v<TIN, float>) {
    float4 u = *(const float4*)(in + (size_t)row * stride + t * 4);
    x0 = u.x; x1 = u.y; x2 = u.z; x3 = u.w;
  } else {
    ushort4 u = *(const ushort4*)(in + (size_t)row * stride + t * 4);
    x0 = us2f(u.x); x1 = us2f(u.y); x2 = us2f(u.z); x3 = us2f(u.w);
  }
  float s = x0 + x1 + x2 + x3;
  float s2 = x0 * x0 + x1 * x1 + x2 * x2 + x3 * x3;
#pragma unroll
  for (int m = 1; m < 64; m <<= 1) {
    s += __shfl_xor(s, m);
    s2 += __shfl_xor(s2, m);
  }
  __shared__ float red[10];
  const int w = t >> 6, lane = t & 63;
  if (lane == 0) { red[w] = s; red[4 + w] = s2; }
  __syncthreads();
  if (t == 0) {
    float S = red[0] + red[1] + red[2] + red[3];
    float S2 = red[4] + red[5] + red[6] + red[7];
    float mu = S / (float)D;
    float var = S2 / (float)D - mu * mu;
    red[8] = mu;
    red[9] = rsqrtf(var + 1e-5f);
  }
  __syncthreads();
  const float mu = red[8], rs = red[9];
  float4 g4 = *(const float4*)(gamma + t * 4);
  float4 b4 = *(const float4*)(beta + t * 4);
  uint2 o;
  o.x = pack_bf16x2(((x0 - mu) * rs * g4.x + b4.x) * sc, ((x1 - mu) * rs * g4.y + b4.y) * sc);
  o.y = pack_bf16x2(((x2 - mu) * rs * g4.z + b4.z) * sc, ((x3 - mu) * rs * g4.w + b4.w) * sc);
  *(uint2*)(out + (size_t)row * D + t * 4) = o;
}

// ---------------- all 3 weight transposes in one launch: z selects tensor ----------------
__global__ __launch_bounds__(256) void transpose3_kernel(
    const float* __restrict__ s0, bf16* __restrict__ d0,   // 1024x2048
    const float* __restrict__ s1, bf16* __restrict__ d1,   // 1024x1024
    const float* __restrict__ s2, bf16* __restrict__ d2)   // 1024x1024
{
  const int z = blockIdx.z;
  if (z > 0 && blockIdx.x >= 16) return;
  const float* in = (z == 0) ? s0 : (z == 1) ? s1 : s2;
  bf16* out = (z == 0) ? d0 : (z == 1) ? d1 : d2;
  const int R = 1024, C = (z == 0) ? 2048 : 1024;
  __shared__ float tile[64][68];
  const int r0 = blockIdx.y * 64, c0 = blockIdx.x * 64;
  const int t = threadIdx.x;
  const int lr = t >> 2, lc = (t & 3) * 16;
  const float* src = in + (size_t)(r0 + lr) * C + (c0 + lc);
#pragma unroll
  for (int i = 0; i < 4; ++i) {
    float4 u = *(const float4*)(src + i * 4);
    tile[lr][lc + i * 4 + 0] = u.x;
    tile[lr][lc + i * 4 + 1] = u.y;
    tile[lr][lc + i * 4 + 2] = u.z;
    tile[lr][lc + i * 4 + 3] = u.w;
  }
  __syncthreads();
  __align__(16) bf16 tmp[16];
#pragma unroll
  for (int j = 0; j < 16; ++j) tmp[j] = __float2bfloat16(tile[lc + j][lr]);
  bf16* dst = out + (size_t)(c0 + lr) * R + (r0 + lc);
  *(bf16x8*)dst       = *(const bf16x8*)&tmp[0];
  *(bf16x8*)(dst + 8) = *(const bf16x8*)&tmp[8];
}

// ---------------- GEMM: C(M,N) = A(M,K) @ Bt(N,K)^T (+bias), bf16 in, fp32 accum ----------------
// dbuf K-loop, raw s_barrier + vmcnt(N) (never 0).
// TMODE 0: row-major store. TMODE 1 (BM=64): vt store via LDS bounce, coalesced:
//   vt[((row>>11)*1024 + col)*2048 + (row&2047)].
template <int BM, int TMODE, typename TOUT>
__global__ __launch_bounds__(256) void gemm_bt_kernel(
    const bf16* __restrict__ A, const bf16* __restrict__ Bt,
    const float* __restrict__ bias, TOUT* __restrict__ C,
    int M, int N, int K, int has_bias)
{
  constexpr int MT = BM / 32;
  constexpr int LA = (BM * 4) / 256;
  __shared__ __align__(16) bf16 lA[2 * BM * 32];
  __shared__ __align__(16) bf16 lB[2 * 128 * 32];
  constexpr int OUTSZ = (TMODE == 1) ? 128 * 68 : 1;
  __shared__ __align__(16) bf16 lOut[OUTSZ];
  const int t = threadIdx.x;
  const int w = t >> 6, lane = t & 63, l15 = lane & 15, quad = lane >> 4;
  const int wy = w >> 1, wx = w & 1;
  const bf16* Ab = A + (size_t)blockIdx.y * BM * K;
  const bf16* Bb = Bt + (size_t)blockIdx.x * 128 * K;
  f32x4 acc[MT][4] = {};

#pragma unroll
  for (int i = 0; i < LA; ++i) {
    int s = i * 256 + t;
    gl_lds16(Ab + (size_t)(s >> 2) * K + (s & 3) * 8, lA + s * 8);
  }
#pragma unroll
  for (int i = 0; i < 2; ++i) {
    int s = i * 256 + t;
    gl_lds16(Bb + (size_t)(s >> 2) * K + (s & 3) * 8, lB + s * 8);
  }

  const int niter = K >> 5;
  for (int it = 0; it < niter; ++it) {
    const int cur = it & 1;
    __builtin_amdgcn_s_barrier();
    {
      int nkc = (it + 1 < niter) ? (it + 1) * 32 : 0;
      bf16* dA = lA + (cur ^ 1) * BM * 32;
      bf16* dB = lB + (cur ^ 1) * 4096;
#pragma unroll
      for (int i = 0; i < LA; ++i) {
        int s = i * 256 + t;
        gl_lds16(Ab + (size_t)(s >> 2) * K + nkc + (s & 3) * 8, dA + s * 8);
      }
#pragma unroll
      for (int i = 0; i < 2; ++i) {
        int s = i * 256 + t;
        gl_lds16(Bb + (size_t)(s >> 2) * K + nkc + (s & 3) * 8, dB + s * 8);
      }
    }
    if constexpr (LA + 2 == 4) asm volatile("s_waitcnt vmcnt(4)" ::: "memory");
    else                       asm volatile("s_waitcnt vmcnt(3)" ::: "memory");
    __builtin_amdgcn_s_barrier();

    const bf16* sA = lA + cur * BM * 32;
    const bf16* sB = lB + cur * 4096;
    bf16x8 af[MT], bfr[4];
#pragma unroll
    for (int mt = 0; mt < MT; ++mt)
      af[mt] = *(const bf16x8*)&sA[(wy * (BM / 2) + mt * 16 + l15) * 32 + quad * 8];
#pragma unroll
    for (int nt = 0; nt < 4; ++nt)
      bfr[nt] = *(const bf16x8*)&sB[(wx * 64 + nt * 16 + l15) * 32 + quad * 8];
#pragma unroll
    for (int mt = 0; mt < MT; ++mt)
#pragma unroll
      for (int nt = 0; nt < 4; ++nt)
        acc[mt][nt] = MFMA_BF16(af[mt], bfr[nt], acc[mt][nt]);
  }

  if constexpr (TMODE == 1) {
    // bounce acc tiles (row = n, col = d) into lOut[d][n], then coalesced stores
    __syncthreads();
#pragma unroll
    for (int mt = 0; mt < MT; ++mt)
#pragma unroll
      for (int nt = 0; nt < 4; ++nt) {
        const int d = wx * 64 + nt * 16 + l15;
        const int n = wy * 32 + mt * 16 + quad * 4;
        uint2 pk;
        pk.x = pack_bf16x2(acc[mt][nt][0], acc[mt][nt][1]);
        pk.y = pack_bf16x2(acc[mt][nt][2], acc[mt][nt][3]);
        *(uint2*)&lOut[d * 68 + n] = pk;
      }
    __syncthreads();
    const int row0 = blockIdx.y * BM;
    const int bidx = row0 >> 11, n0 = row0 & 2047;
    const int col0 = blockIdx.x * 128;
    const int d = t >> 1, half = (t & 1) * 32;
    const bf16* src = &lOut[d * 68 + half];
    __align__(16) bf16 tmp[32];
#pragma unroll
    for (int j = 0; j < 8; ++j)
      *(uint2*)&tmp[j * 4] = *(const uint2*)(src + j * 4);
    bf16* g = (bf16*)C + ((size_t)(bidx << 10) + col0 + d) * 2048 + n0 + half;
#pragma unroll
    for (int j = 0; j < 4; ++j)
      *(bf16x8*)(g + j * 8) = *(const bf16x8*)&tmp[j * 8];
  } else {
    const int row_base = blockIdx.y * BM + wy * (BM / 2);
    const int col_base = blockIdx.x * 128 + wx * 64;
#pragma unroll
    for (int mt = 0; mt < MT; ++mt)
#pragma unroll
      for (int nt = 0; nt < 4; ++nt) {
        const int col = col_base + nt * 16 + l15;
        const float bb = has_bias ? bias[col] : 0.0f;
#pragma unroll
        for (int r = 0; r < 4; ++r) {
          const int row = row_base + mt * 16 + quad * 4 + r;
          float v = acc[mt][nt][r] + bb;
          if constexpr (std::is_same_v<TOUT, bf16>)
            C[(size_t)row * N + col] = __float2bfloat16(v);
          else
            C[(size_t)row * N + col] = v;
        }
      }
  }
}

// ---------------- Flash attention (R7) ----------------
// K staged to LDS (dbuf, swizzled); V frags read DIRECT from global vt (L2-
// resident) — no V staging, no V LDS reads. qln pre-scaled by SCALE*log2e;
// p = v_exp_f32; P packed via v_perm trunc, wave-private LDS round-trip.
// vmcnt: iter top issues vf(8)+Knext(2); vmcnt(10) = K-cur staged;
// vmcnt(2) before PV = vf done, K-next still in flight. Never drains to 0.
__global__ __launch_bounds__(256) void flash_kernel(
    const bf16* __restrict__ Q, const bf16* __restrict__ Km,
    const bf16* __restrict__ Vt, bf16* __restrict__ O)
{
  __shared__ __align__(16) bf16 smem[9216 + 8192 + 8192];
  bf16* lP = smem;                 // 4 waves x 32x72
  bf16* lQ = smem + 9216;          // 128x64
  bf16* lKb = smem + 9216 + 8192;  // 2 x 64x64
  const int t = threadIdx.x;
  const int w = t >> 6, lane = t & 63, l15 = lane & 15, quad = lane >> 4;
  const int qt = blockIdx.x, bh = blockIdx.y;
  const int b = bh >> 4, h = bh & 15;
  const int qrow0 = b * 2048 + qt * 128;
  const bf16* qbase = Q + (size_t)qrow0 * 1024 + h * 64;
  const bf16* kbase = Km + ((size_t)(b * 2048)) * 1024 + h * 64;
  const bf16* vbase = Vt + ((size_t)(b * 1024 + h * 64)) * 2048;
  bf16* lPm = lP + w * (32 * 72);

  const int sr0 = t >> 3, sc0 = ((t & 7) ^ (sr0 & 7)) << 3;
  const int sr1 = (256 + t) >> 3, sc1 = (((256 + t) & 7) ^ (sr1 & 7)) << 3;
  const bf16* kp0 = kbase + sr0 * 1024 + sc0;
  const bf16* kp1 = kbase + sr1 * 1024 + sc1;
  const bf16* vlane = vbase + l15 * 2048 + quad * 8;  // + dt*32768 + kt*64 + c*32

  // prologue: Q (4 slots/thread) then K tile 0 (2)
#pragma unroll
  for (int i = 0; i < 4; ++i) {
    int s = i * 256 + t;
    int row = s >> 3, c = (s & 7) ^ (row & 7);
    gl_lds16(qbase + (size_t)row * 1024 + (c << 3), lQ + s * 8);
  }
  gl_lds16(kp0, lKb + t * 8);
  gl_lds16(kp1, lKb + (256 + t) * 8);
  asm volatile("s_waitcnt vmcnt(2)" ::: "memory");  // Q done, K0 in flight
  __builtin_amdgcn_s_barrier();

  const int sw = (quad ^ (l15 & 7)) << 3;
  bf16x8 qf[2][2];
#pragma unroll
  for (int mset = 0; mset < 2; ++mset) {
    const int row = w * 32 + mset * 16 + l15;
    qf[mset][0] = *(const bf16x8*)&lQ[row * 64 + sw];
    qf[mset][1] = *(const bf16x8*)&lQ[row * 64 + (sw ^ 32)];
  }

  f32x4 o_acc[4][2] = {};
  f32x4 l_vec[2] = {};

  for (int kt = 0; kt < 32; ++kt) {
    const int cur = kt & 1;
    bf16* lK = lKb + cur * 4096;
    bf16* lKn = lKb + (cur ^ 1) * 4096;

    __builtin_amdgcn_s_barrier();  // all waves done reading lK cur^1

    // V frags for cur tile: direct global b128s, issued early (L2 latency cover)
    bf16x8 vf[4][2];
#pragma unroll
    for (int dt = 0; dt < 4; ++dt) {
      const bf16* vp = vlane + dt * (16 * 2048) + kt * 64;
      vf[dt][0] = *(const bf16x8*)vp;
      vf[dt][1] = *(const bf16x8*)(vp + 32);
    }
    // stage next K tile into the other buffer
    {
      const int ktn = (kt + 1) & 31;
      const int ko = ktn << 16;  // ktn*64 rows * 1024
      gl_lds16(kp0 + ko, lKn + t * 8);
      gl_lds16(kp1 + ko, lKn + (256 + t) * 8);
    }
    asm volatile("s_waitcnt vmcnt(10)" ::: "memory");  // K-cur (2 oldest) retired
    __builtin_amdgcn_s_barrier();                      // everyone's K-cur visible

    bf16x8 kf[4][2];
#pragma unroll
    for (int nt = 0; nt < 4; ++nt) {
      kf[nt][0] = *(const bf16x8*)&lK[(nt * 16 + l15) * 64 + sw];
      kf[nt][1] = *(const bf16x8*)&lK[(nt * 16 + l15) * 64 + (sw ^ 32)];
    }

    // S^T (log2-domain) + v_exp + truncating pack + P write (wave-private)
#pragma unroll
    for (int mset = 0; mset < 2; ++mset) {
#pragma unroll
      for (int nt = 0; nt < 4; ++nt) {
        f32x4 z = {};
        z = MFMA_BF16(kf[nt][0], qf[mset][0], z);
        z = MFMA_BF16(kf[nt][1], qf[mset][1], z);
        f32x4 p;
#pragma unroll
        for (int r = 0; r < 4; ++r) p[r] = __builtin_amdgcn_exp2f(z[r]);
        l_vec[mset] += p;
        uint2 pk;
        pk.x = pack_bf16x2_trunc(p[0], p[1]);
        pk.y = pack_bf16x2_trunc(p[2], p[3]);
        *(uint2*)&lPm[(mset * 16 + l15) * 72 + nt * 16 + quad * 4] = pk;
      }
    }
    asm volatile("s_waitcnt lgkmcnt(0)" ::: "memory");  // P writes landed
    asm volatile("s_waitcnt vmcnt(2)" ::: "memory");    // vf done; K-next in flight

#pragma unroll
    for (int mset = 0; mset < 2; ++mset) {
      const bf16* pr = &lPm[(mset * 16 + l15) * 72 + quad * 8];
      bf16x8 pf0 = *(const bf16x8*)pr;
      bf16x8 pf1 = *(const bf16x8*)(pr + 32);
#pragma unroll
      for (int dt = 0; dt < 4; ++dt) {
        o_acc[dt][mset] = MFMA_BF16(vf[dt][0], pf0, o_acc[dt][mset]);
        o_acc[dt][mset] = MFMA_BF16(vf[dt][1], pf1, o_acc[dt][mset]);
      }
    }
  }

  // epilogue: cross-quad row sums + divide + store O^T fragments
#pragma unroll
  for (int mset = 0; mset < 2; ++mset) {
    float tsum = l_vec[mset][0] + l_vec[mset][1] + l_vec[mset][2] + l_vec[mset][3];
    tsum += __shfl_xor(tsum, 16);
    tsum += __shfl_xor(tsum, 32);
    const float inv = 1.0f / tsum;
    const int m = qrow0 + w * 32 + mset * 16 + l15;
#pragma unroll
    for (int dt = 0; dt < 4; ++dt) {
      uint2 ok;
      ok.x = pack_bf16x2(o_acc[dt][mset][0] * inv, o_acc[dt][mset][1] * inv);
      ok.y = pack_bf16x2(o_acc[dt][mset][2] * inv, o_acc[dt][mset][3] * inv);
      *(uint2*)&O[(size_t)m * 1024 + h * 64 + dt * 16 + quad * 4] = ok;
    }
  }
}

extern "C" void kernel_launch(void* const* d_in, const int* in_sizes, int n_in,
                              void* d_out, int out_size, void* d_ws, size_t ws_size,
                              hipStream_t stream)
{
  (void)in_sizes; (void)n_in; (void)out_size; (void)ws_size;
  const float* keys   = (const float*)d_in[0];
  const float* values = (const float*)d_in[1];
  const float* qk_g   = (const float*)d_in[2];
  const float* qk_b   = (const float*)d_in[3];
  const float* val_g  = (const float*)d_in[4];
  const float* val_b  = (const float*)d_in[5];
  const float* key_g  = (const float*)d_in[6];
  const float* key_b  = (const float*)d_in[7];
  const float* qry_g  = (const float*)d_in[8];
  const float* qry_b  = (const float*)d_in[9];
  const float* w_qk   = (const float*)d_in[10];
  const float* w_v    = (const float*)d_in[11];
  const float* w_out  = (const float*)d_in[12];
  const float* b_out  = (const float*)d_in[13];
  float* out = (float*)d_out;

  const float CEXP = 0.03125f * 1.44269504f;  // ID^-0.5 * log2(e), folded into q-LN

  char* ws = (char*)d_ws;
  const size_t MB = 1024 * 1024;
  bf16* keys_ln   = (bf16*)(ws + 0);        // 8MB
  bf16* values_ln = (bf16*)(ws + 8 * MB);   // 8MB
  bf16* qk        = (bf16*)(ws + 16 * MB);  // 16MB
  bf16* attn      = (bf16*)(ws + 16 * MB);  // 8MB (qk dead)
  bf16* vt        = (bf16*)(ws + 24 * MB);  // 8MB
  bf16* qln       = (bf16*)(ws + 32 * MB);  // 8MB
  bf16* kln       = (bf16*)(ws + 40 * MB);  // 8MB
  bf16* wqkT      = (bf16*)(ws + 48 * MB);  // 4MB
  bf16* wvT       = (bf16*)(ws + 52 * MB);  // 2MB
  bf16* woutT     = (bf16*)(ws + 54 * MB);  // 2MB

  // L1: both input layernorms
  ln2_kernel<float><<<dim3(4096, 2), 256, 0, stream>>>(
      keys, values, 1024, qk_g, qk_b, val_g, val_b, keys_ln, values_ln, 1024, 1.0f, 1.0f);
  // L2: all weight transposes
  transpose3_kernel<<<dim3(32, 16, 3), 256, 0, stream>>>(w_qk, wqkT, w_v, wvT, w_out, woutT);
  // L3: qk = keys_ln @ w_qk (4096 x 2048)
  gemm_bt_kernel<128, 0, bf16><<<dim3(16, 32), 256, 0, stream>>>(keys_ln, wqkT, nullptr, qk, 4096, 2048, 1024, 0);
  // L4: q/k layernorms; qln pre-scaled by CEXP
  ln2_kernel<bf16><<<dim3(4096, 2), 256, 0, stream>>>(
      qk, qk + 1024, 2048, qry_g, qry_b, key_g, key_b, qln, kln, 1024, CEXP, 1.0f);
  // L5: v = values_ln @ w_v, stored transposed into vt via LDS bounce
  gemm_bt_kernel<64, 1, bf16><<<dim3(8, 64), 256, 0, stream>>>(values_ln, wvT, nullptr, vt, 4096, 1024, 1024, 0);
  // L6: flash attention -> attn
  flash_kernel<<<dim3(16, 32), 256, 0, stream>>>(qln, kln, vt, attn);
  // L7: out = attn @ w_out + b_out (fp32 out)
  gemm_bt_kernel<64, 0, float><<<dim3(8, 64), 256, 0, stream>>>(attn, woutT, b_out, out, 4096, 1024, 1024, 1);
}

// Round 8
// 256.142 us; speedup vs baseline: 1.0532x; 1.0532x over previous
//
#include <hip/hip_runtime.h>
#include <hip/hip_bf16.h>
#include <type_traits>

// SelfAttention fused block, MI355X/gfx950.
// R8: flash reverted to R6 (measured best: K+V gl_lds dbuf, vmcnt(4), v_exp,
//     v_perm pack). GEMMs reverted to single-buffered 2-barrier structure
//     (dbuf regressed, per R6 + m99/m131-141) with smaller tiles for 4
//     blocks/CU: G3 64x128, G5/G7 64x64 (all 1024-block grids). 7 launches.

typedef __hip_bfloat16 bf16;
typedef __attribute__((ext_vector_type(8))) short bf16x8;
typedef __attribute__((ext_vector_type(4))) float f32x4;

#define MFMA_BF16(a, b, c) __builtin_amdgcn_mfma_f32_16x16x32_bf16((a), (b), (c), 0, 0, 0)

__device__ __forceinline__ float us2f(unsigned short u) {
  unsigned int v = ((unsigned int)u) << 16;
  return __builtin_bit_cast(float, v);
}

__device__ __forceinline__ unsigned pack_bf16x2(float a, float b) {  // RNE (epilogues)
  union { __hip_bfloat162 h; unsigned u; } cv;
  cv.h = __float22bfloat162_rn(float2{a, b});
  return cv.u;
}

__device__ __forceinline__ unsigned pack_bf16x2_trunc(float a, float b) {  // 1x v_perm
  return __builtin_amdgcn_perm(__builtin_bit_cast(unsigned, b),
                               __builtin_bit_cast(unsigned, a), 0x07060302u);
}

// async global->LDS, 16B per lane; lane i's dest = wave-uniform base + i*16
__device__ __forceinline__ void gl_lds16(const bf16* g, bf16* l) {
  __builtin_amdgcn_global_load_lds(
      (const __attribute__((address_space(1))) void*)g,
      (__attribute__((address_space(3))) void*)l, 16, 0, 0);
}

// ---------------- fused pair of LayerNorms: grid (rows, 2); out scaled by sc ----------------
template <typename TIN>
__global__ __launch_bounds__(256) void ln2_kernel(
    const TIN* __restrict__ in0, const TIN* __restrict__ in1, int stride,
    const float* __restrict__ g0, const float* __restrict__ b0,
    const float* __restrict__ g1, const float* __restrict__ b1,
    bf16* __restrict__ out0, bf16* __restrict__ out1, int D,
    float sc0, float sc1)
{
  const int which = blockIdx.y;
  const TIN* in = which ? in1 : in0;
  const float* gamma = which ? g1 : g0;
  const float* beta = which ? b1 : b0;
  bf16* out = which ? out1 : out0;
  const float sc = which ? sc1 : sc0;
  const int row = blockIdx.x;
  const int t = threadIdx.x;
  float x0, x1, x2, x3;
  if constexpr (std::is_same_v<TIN, float>) {
    float4 u = *(const float4*)(in + (size_t)row * stride + t * 4);
    x0 = u.x; x1 = u.y; x2 = u.z; x3 = u.w;
  } else {
    ushort4 u = *(const ushort4*)(in + (size_t)row * stride + t * 4);
    x0 = us2f(u.x); x1 = us2f(u.y); x2 = us2f(u.z); x3 = us2f(u.w);
  }
  float s = x0 + x1 + x2 + x3;
  float s2 = x0 * x0 + x1 * x1 + x2 * x2 + x3 * x3;
#pragma unroll
  for (int m = 1; m < 64; m <<= 1) {
    s += __shfl_xor(s, m);
    s2 += __shfl_xor(s2, m);
  }
  __shared__ float red[10];
  const int w = t >> 6, lane = t & 63;
  if (lane == 0) { red[w] = s; red[4 + w] = s2; }
  __syncthreads();
  if (t == 0) {
    float S = red[0] + red[1] + red[2] + red[3];
    float S2 = red[4] + red[5] + red[6] + red[7];
    float mu = S / (float)D;
    float var = S2 / (float)D - mu * mu;
    red[8] = mu;
    red[9] = rsqrtf(var + 1e-5f);
  }
  __syncthreads();
  const float mu = red[8], rs = red[9];
  float4 g4 = *(const float4*)(gamma + t * 4);
  float4 b4 = *(const float4*)(beta + t * 4);
  uint2 o;
  o.x = pack_bf16x2(((x0 - mu) * rs * g4.x + b4.x) * sc, ((x1 - mu) * rs * g4.y + b4.y) * sc);
  o.y = pack_bf16x2(((x2 - mu) * rs * g4.z + b4.z) * sc, ((x3 - mu) * rs * g4.w + b4.w) * sc);
  *(uint2*)(out + (size_t)row * D + t * 4) = o;
}

// ---------------- all 3 weight transposes in one launch: z selects tensor ----------------
__global__ __launch_bounds__(256) void transpose3_kernel(
    const float* __restrict__ s0, bf16* __restrict__ d0,   // 1024x2048
    const float* __restrict__ s1, bf16* __restrict__ d1,   // 1024x1024
    const float* __restrict__ s2, bf16* __restrict__ d2)   // 1024x1024
{
  const int z = blockIdx.z;
  if (z > 0 && blockIdx.x >= 16) return;
  const float* in = (z == 0) ? s0 : (z == 1) ? s1 : s2;
  bf16* out = (z == 0) ? d0 : (z == 1) ? d1 : d2;
  const int R = 1024, C = (z == 0) ? 2048 : 1024;
  __shared__ float tile[64][68];
  const int r0 = blockIdx.y * 64, c0 = blockIdx.x * 64;
  const int t = threadIdx.x;
  const int lr = t >> 2, lc = (t & 3) * 16;
  const float* src = in + (size_t)(r0 + lr) * C + (c0 + lc);
#pragma unroll
  for (int i = 0; i < 4; ++i) {
    float4 u = *(const float4*)(src + i * 4);
    tile[lr][lc + i * 4 + 0] = u.x;
    tile[lr][lc + i * 4 + 1] = u.y;
    tile[lr][lc + i * 4 + 2] = u.z;
    tile[lr][lc + i * 4 + 3] = u.w;
  }
  __syncthreads();
  __align__(16) bf16 tmp[16];
#pragma unroll
  for (int j = 0; j < 16; ++j) tmp[j] = __float2bfloat16(tile[lc + j][lr]);
  bf16* dst = out + (size_t)(c0 + lr) * R + (r0 + lc);
  *(bf16x8*)dst       = *(const bf16x8*)&tmp[0];
  *(bf16x8*)(dst + 8) = *(const bf16x8*)&tmp[8];
}

// ---------------- GEMM: C(M,N) = A(M,K) @ Bt(N,K)^T (+bias), bf16 in, fp32 accum ----------------
// Single-buffered 2-barrier K-loop (m97 structure). 2x2 waves, wave tile
// (BM/2)x(BN/2). grid = (N/BN, M/BM). TMODE 1 (BM=BN=64): coalesced vt store
// via LDS bounce: vt[((row>>11)*1024 + col)*2048 + (row&2047)].
template <int BM, int BN, int TMODE, typename TOUT>
__global__ __launch_bounds__(256) void gemm_bt_kernel(
    const bf16* __restrict__ A, const bf16* __restrict__ Bt,
    const float* __restrict__ bias, TOUT* __restrict__ C,
    int M, int N, int K, int has_bias)
{
  constexpr int MT = BM / 32, NT = BN / 32;
  constexpr int ASL = (BM * 4) / 256, BSL = (BN * 4) / 256;
  __shared__ __align__(16) bf16 lA[BM * 32];
  __shared__ __align__(16) bf16 lB[BN * 32];
  constexpr int OUTSZ = (TMODE == 1) ? 64 * 68 : 1;
  __shared__ __align__(16) bf16 lOut[OUTSZ];
  const int t = threadIdx.x;
  const int w = t >> 6, lane = t & 63, l15 = lane & 15, quad = lane >> 4;
  const int wy = w >> 1, wx = w & 1;
  const bf16* Ab = A + (size_t)blockIdx.y * BM * K;
  const bf16* Bb = Bt + (size_t)blockIdx.x * BN * K;
  f32x4 acc[MT][NT] = {};

  for (int kc = 0; kc < K; kc += 32) {
    __syncthreads();  // prior iter's frag reads done before overwrite
#pragma unroll
    for (int i = 0; i < ASL; ++i) {
      int s = i * 256 + t;
      gl_lds16(Ab + (size_t)(s >> 2) * K + kc + (s & 3) * 8, lA + s * 8);
    }
#pragma unroll
    for (int i = 0; i < BSL; ++i) {
      int s = i * 256 + t;
      gl_lds16(Bb + (size_t)(s >> 2) * K + kc + (s & 3) * 8, lB + s * 8);
    }
    __syncthreads();  // vmcnt drained: staged data visible
    bf16x8 af[MT], bfr[NT];
#pragma unroll
    for (int mt = 0; mt < MT; ++mt)
      af[mt] = *(const bf16x8*)&lA[(wy * (BM / 2) + mt * 16 + l15) * 32 + quad * 8];
#pragma unroll
    for (int nt = 0; nt < NT; ++nt)
      bfr[nt] = *(const bf16x8*)&lB[(wx * (BN / 2) + nt * 16 + l15) * 32 + quad * 8];
#pragma unroll
    for (int mt = 0; mt < MT; ++mt)
#pragma unroll
      for (int nt = 0; nt < NT; ++nt)
        acc[mt][nt] = MFMA_BF16(af[mt], bfr[nt], acc[mt][nt]);
  }

  if constexpr (TMODE == 1) {
    // acc: row n = wy*32+mt*16+quad*4+r, col d = wx*32+nt*16+l15 -> lOut[d][n]
    __syncthreads();
#pragma unroll
    for (int mt = 0; mt < MT; ++mt)
#pragma unroll
      for (int nt = 0; nt < NT; ++nt) {
        const int d = wx * 32 + nt * 16 + l15;
        const int n = wy * 32 + mt * 16 + quad * 4;
        uint2 pk;
        pk.x = pack_bf16x2(acc[mt][nt][0], acc[mt][nt][1]);
        pk.y = pack_bf16x2(acc[mt][nt][2], acc[mt][nt][3]);
        *(uint2*)&lOut[d * 68 + n] = pk;
      }
    __syncthreads();
    const int row0 = blockIdx.y * BM;
    const int bidx = row0 >> 11, n0 = row0 & 2047;
    const int col0 = blockIdx.x * BN;
    const int d = t >> 2, nh = (t & 3) * 16;
    __align__(16) bf16 tmp[16];
#pragma unroll
    for (int j = 0; j < 4; ++j)
      *(uint2*)&tmp[j * 4] = *(const uint2*)&lOut[d * 68 + nh + j * 4];
    bf16* g = (bf16*)C + ((size_t)(bidx << 10) + col0 + d) * 2048 + n0 + nh;
    *(bf16x8*)g       = *(const bf16x8*)&tmp[0];
    *(bf16x8*)(g + 8) = *(const bf16x8*)&tmp[8];
  } else {
    const int row_base = blockIdx.y * BM + wy * (BM / 2);
    const int col_base = blockIdx.x * BN + wx * (BN / 2);
#pragma unroll
    for (int mt = 0; mt < MT; ++mt)
#pragma unroll
      for (int nt = 0; nt < NT; ++nt) {
        const int col = col_base + nt * 16 + l15;
        const float bb = has_bias ? bias[col] : 0.0f;
#pragma unroll
        for (int r = 0; r < 4; ++r) {
          const int row = row_base + mt * 16 + quad * 4 + r;
          float v = acc[mt][nt][r] + bb;
          if constexpr (std::is_same_v<TOUT, bf16>)
            C[(size_t)row * N + col] = __float2bfloat16(v);
          else
            C[(size_t)row * N + col] = v;
        }
      }
  }
}

// ---------------- Flash attention (R6 design — measured best) ----------------
// qln pre-scaled by SCALE*log2e -> S^T MFMA gives log2-domain logits; p =
// v_exp_f32. P packed via v_perm trunc. K/V dbuf via gl_lds, raw s_barrier +
// vmcnt(4) (never 0). P round-trip wave-private (lgkmcnt(0) only).
__global__ __launch_bounds__(256) void flash_kernel(
    const bf16* __restrict__ Q, const bf16* __restrict__ Km,
    const bf16* __restrict__ Vt, bf16* __restrict__ O)
{
  __shared__ __align__(16) bf16 smem[9216 + 8192 + 8192 + 8192];
  bf16* lP = smem;                         // 4 waves x 32x72
  bf16* lQ = smem + 9216;                  // 128x64
  bf16* lKb = smem + 9216 + 8192;          // 2 x 64x64
  bf16* lVb = smem + 9216 + 8192 + 8192;   // 2 x 64x64
  const int t = threadIdx.x;
  const int w = t >> 6, lane = t & 63, l15 = lane & 15, quad = lane >> 4;
  const int qt = blockIdx.x, bh = blockIdx.y;
  const int b = bh >> 4, h = bh & 15;
  const int qrow0 = b * 2048 + qt * 128;
  const bf16* qbase = Q + (size_t)qrow0 * 1024 + h * 64;
  const bf16* kbase = Km + ((size_t)(b * 2048)) * 1024 + h * 64;
  const bf16* vbase = Vt + ((size_t)(b * 1024 + h * 64)) * 2048;
  bf16* lPm = lP + w * (32 * 72);

  const int sr0 = t >> 3, sc0 = ((t & 7) ^ (sr0 & 7)) << 3;
  const int sr1 = (256 + t) >> 3, sc1 = (((256 + t) & 7) ^ (sr1 & 7)) << 3;
  const bf16* kp0 = kbase + sr0 * 1024 + sc0;
  const bf16* kp1 = kbase + sr1 * 1024 + sc1;
  const bf16* vp0 = vbase + sr0 * 2048 + sc0;
  const bf16* vp1 = vbase + sr1 * 2048 + sc1;

  // prologue: stage Q (4) + K/V tile 0 (4)
#pragma unroll
  for (int i = 0; i < 4; ++i) {
    int s = i * 256 + t;
    int row = s >> 3, c = (s & 7) ^ (row & 7);
    gl_lds16(qbase + (size_t)row * 1024 + (c << 3), lQ + s * 8);
  }
  gl_lds16(kp0, lKb + t * 8);
  gl_lds16(kp1, lKb + (256 + t) * 8);
  gl_lds16(vp0, lVb + t * 8);
  gl_lds16(vp1, lVb + (256 + t) * 8);
  asm volatile("s_waitcnt vmcnt(4)" ::: "memory");  // Q done (FIFO), tile0 in flight
  __builtin_amdgcn_s_barrier();

  const int sw = (quad ^ (l15 & 7)) << 3;
  bf16x8 qf[2][2];
#pragma unroll
  for (int mset = 0; mset < 2; ++mset) {
    const int row = w * 32 + mset * 16 + l15;
    qf[mset][0] = *(const bf16x8*)&lQ[row * 64 + sw];
    qf[mset][1] = *(const bf16x8*)&lQ[row * 64 + (sw ^ 32)];
  }

  f32x4 o_acc[4][2] = {};   // [dt][mset]: O^T row d = dt*16+quad*4+r, col m = mset*16+l15
  f32x4 l_vec[2] = {};      // in-lane partial row sums

  for (int kt = 0; kt < 32; ++kt) {
    const int cur = kt & 1;
    bf16* lK = lKb + cur * 4096;
    bf16* lV = lVb + cur * 4096;
    bf16* lKn = lKb + (cur ^ 1) * 4096;
    bf16* lVn = lVb + (cur ^ 1) * 4096;

    __builtin_amdgcn_s_barrier();  // all waves done reading buf cur^1
    {
      const int ktn = (kt + 1) & 31;  // wrap: restage tile 0 into dead buf
      const int ko = ktn << 16;       // ktn*64 rows * 1024
      const int vo = ktn << 6;        // ktn*64 cols
      gl_lds16(kp0 + ko, lKn + t * 8);
      gl_lds16(kp1 + ko, lKn + (256 + t) * 8);
      gl_lds16(vp0 + vo, lVn + t * 8);
      gl_lds16(vp1 + vo, lVn + (256 + t) * 8);
    }
    asm volatile("s_waitcnt vmcnt(4)" ::: "memory");
    __builtin_amdgcn_s_barrier();

    bf16x8 kf[4][2];
#pragma unroll
    for (int nt = 0; nt < 4; ++nt) {
      kf[nt][0] = *(const bf16x8*)&lK[(nt * 16 + l15) * 64 + sw];
      kf[nt][1] = *(const bf16x8*)&lK[(nt * 16 + l15) * 64 + (sw ^ 32)];
    }

    // S^T (log2-domain) + v_exp + truncating pack + P write (wave-private)
#pragma unroll
    for (int mset = 0; mset < 2; ++mset) {
#pragma unroll
      for (int nt = 0; nt < 4; ++nt) {
        f32x4 z = {};
        z = MFMA_BF16(kf[nt][0], qf[mset][0], z);
        z = MFMA_BF16(kf[nt][1], qf[mset][1], z);
        f32x4 p;
#pragma unroll
        for (int r = 0; r < 4; ++r) p[r] = __builtin_amdgcn_exp2f(z[r]);
        l_vec[mset] += p;
        uint2 pk;
        pk.x = pack_bf16x2_trunc(p[0], p[1]);
        pk.y = pack_bf16x2_trunc(p[2], p[3]);
        *(uint2*)&lPm[(mset * 16 + l15) * 72 + nt * 16 + quad * 4] = pk;
      }
    }

    bf16x8 vf[4][2];
#pragma unroll
    for (int dt = 0; dt < 4; ++dt) {
      vf[dt][0] = *(const bf16x8*)&lV[(dt * 16 + l15) * 64 + sw];
      vf[dt][1] = *(const bf16x8*)&lV[(dt * 16 + l15) * 64 + (sw ^ 32)];
    }
    asm volatile("s_waitcnt lgkmcnt(0)" ::: "memory");  // P writes landed

#pragma unroll
    for (int mset = 0; mset < 2; ++mset) {
      const bf16* pr = &lPm[(mset * 16 + l15) * 72 + quad * 8];
      bf16x8 pf0 = *(const bf16x8*)pr;
      bf16x8 pf1 = *(const bf16x8*)(pr + 32);
#pragma unroll
      for (int dt = 0; dt < 4; ++dt) {
        o_acc[dt][mset] = MFMA_BF16(vf[dt][0], pf0, o_acc[dt][mset]);
        o_acc[dt][mset] = MFMA_BF16(vf[dt][1], pf1, o_acc[dt][mset]);
      }
    }
  }

  // epilogue: cross-quad row sums + divide + store O^T fragments
#pragma unroll
  for (int mset = 0; mset < 2; ++mset) {
    float tsum = l_vec[mset][0] + l_vec[mset][1] + l_vec[mset][2] + l_vec[mset][3];
    tsum += __shfl_xor(tsum, 16);
    tsum += __shfl_xor(tsum, 32);
    const float inv = 1.0f / tsum;
    const int m = qrow0 + w * 32 + mset * 16 + l15;
#pragma unroll
    for (int dt = 0; dt < 4; ++dt) {
      uint2 ok;
      ok.x = pack_bf16x2(o_acc[dt][mset][0] * inv, o_acc[dt][mset][1] * inv);
      ok.y = pack_bf16x2(o_acc[dt][mset][2] * inv, o_acc[dt][mset][3] * inv);
      *(uint2*)&O[(size_t)m * 1024 + h * 64 + dt * 16 + quad * 4] = ok;
    }
  }
}

extern "C" void kernel_launch(void* const* d_in, const int* in_sizes, int n_in,
                              void* d_out, int out_size, void* d_ws, size_t ws_size,
                              hipStream_t stream)
{
  (void)in_sizes; (void)n_in; (void)out_size; (void)ws_size;
  const float* keys   = (const float*)d_in[0];
  const float* values = (const float*)d_in[1];
  const float* qk_g   = (const float*)d_in[2];
  const float* qk_b   = (const float*)d_in[3];
  const float* val_g  = (const float*)d_in[4];
  const float* val_b  = (const float*)d_in[5];
  const float* key_g  = (const float*)d_in[6];
  const float* key_b  = (const float*)d_in[7];
  const float* qry_g  = (const float*)d_in[8];
  const float* qry_b  = (const float*)d_in[9];
  const float* w_qk   = (const float*)d_in[10];
  const float* w_v    = (const float*)d_in[11];
  const float* w_out  = (const float*)d_in[12];
  const float* b_out  = (const float*)d_in[13];
  float* out = (float*)d_out;

  const float CEXP = 0.03125f * 1.44269504f;  // ID^-0.5 * log2(e), folded into q-LN

  char* ws = (char*)d_ws;
  const size_t MB = 1024 * 1024;
  bf16* keys_ln   = (bf16*)(ws + 0);        // 8MB
  bf16* values_ln = (bf16*)(ws + 8 * MB);   // 8MB
  bf16* qk        = (bf16*)(ws + 16 * MB);  // 16MB
  bf16* attn      = (bf16*)(ws + 16 * MB);  // 8MB (qk dead)
  bf16* vt        = (bf16*)(ws + 24 * MB);  // 8MB
  bf16* qln       = (bf16*)(ws + 32 * MB);  // 8MB
  bf16* kln       = (bf16*)(ws + 40 * MB);  // 8MB
  bf16* wqkT      = (bf16*)(ws + 48 * MB);  // 4MB
  bf16* wvT       = (bf16*)(ws + 52 * MB);  // 2MB
  bf16* woutT     = (bf16*)(ws + 54 * MB);  // 2MB

  // L1: both input layernorms
  ln2_kernel<float><<<dim3(4096, 2), 256, 0, stream>>>(
      keys, values, 1024, qk_g, qk_b, val_g, val_b, keys_ln, values_ln, 1024, 1.0f, 1.0f);
  // L2: all weight transposes
  transpose3_kernel<<<dim3(32, 16, 3), 256, 0, stream>>>(w_qk, wqkT, w_v, wvT, w_out, woutT);
  // L3: qk = keys_ln @ w_qk (4096x2048), 64x128 tiles -> 1024 blocks (4/CU)
  gemm_bt_kernel<64, 128, 0, bf16><<<dim3(16, 64), 256, 0, stream>>>(keys_ln, wqkT, nullptr, qk, 4096, 2048, 1024, 0);
  // L4: q/k layernorms; qln pre-scaled by CEXP
  ln2_kernel<bf16><<<dim3(4096, 2), 256, 0, stream>>>(
      qk, qk + 1024, 2048, qry_g, qry_b, key_g, key_b, qln, kln, 1024, CEXP, 1.0f);
  // L5: v = values_ln @ w_v -> vt (transposed store), 64x64 tiles -> 1024 blocks
  gemm_bt_kernel<64, 64, 1, bf16><<<dim3(16, 64), 256, 0, stream>>>(values_ln, wvT, nullptr, vt, 4096, 1024, 1024, 0);
  // L6: flash attention -> attn
  flash_kernel<<<dim3(16, 32), 256, 0, stream>>>(qln, kln, vt, attn);
  // L7: out = attn @ w_out + b_out (fp32 out), 64x64 tiles -> 1024 blocks
  gemm_bt_kernel<64, 64, 0, float><<<dim3(16, 64), 256, 0, stream>>>(attn, woutT, b_out, out, 4096, 1024, 1024, 1);
}

// Round 9
// 248.610 us; speedup vs baseline: 1.0851x; 1.0303x over previous
//
#include <hip/hip_runtime.h>
#include <hip/hip_bf16.h>
#include <type_traits>

// SelfAttention fused block, MI355X/gfx950.
// R9: GEMMs move to BK=64 (16 iters, 16 MFMA/wave per barrier pair — 2x the
//     MFMA:barrier ratio of BK=32) with flash-style XOR chunk swizzle for
//     conflict-free b128 frag reads on 128B LDS rows. Flash = R6 (measured
//     best). 7 launches.

typedef __hip_bfloat16 bf16;
typedef __attribute__((ext_vector_type(8))) short bf16x8;
typedef __attribute__((ext_vector_type(4))) float f32x4;

#define MFMA_BF16(a, b, c) __builtin_amdgcn_mfma_f32_16x16x32_bf16((a), (b), (c), 0, 0, 0)

__device__ __forceinline__ float us2f(unsigned short u) {
  unsigned int v = ((unsigned int)u) << 16;
  return __builtin_bit_cast(float, v);
}

__device__ __forceinline__ unsigned pack_bf16x2(float a, float b) {  // RNE (epilogues)
  union { __hip_bfloat162 h; unsigned u; } cv;
  cv.h = __float22bfloat162_rn(float2{a, b});
  return cv.u;
}

__device__ __forceinline__ unsigned pack_bf16x2_trunc(float a, float b) {  // 1x v_perm
  return __builtin_amdgcn_perm(__builtin_bit_cast(unsigned, b),
                               __builtin_bit_cast(unsigned, a), 0x07060302u);
}

// async global->LDS, 16B per lane; lane i's dest = wave-uniform base + i*16
__device__ __forceinline__ void gl_lds16(const bf16* g, bf16* l) {
  __builtin_amdgcn_global_load_lds(
      (const __attribute__((address_space(1))) void*)g,
      (__attribute__((address_space(3))) void*)l, 16, 0, 0);
}

// ---------------- fused pair of LayerNorms: grid (rows, 2); out scaled by sc ----------------
template <typename TIN>
__global__ __launch_bounds__(256) void ln2_kernel(
    const TIN* __restrict__ in0, const TIN* __restrict__ in1, int stride,
    const float* __restrict__ g0, const float* __restrict__ b0,
    const float* __restrict__ g1, const float* __restrict__ b1,
    bf16* __restrict__ out0, bf16* __restrict__ out1, int D,
    float sc0, float sc1)
{
  const int which = blockIdx.y;
  const TIN* in = which ? in1 : in0;
  const float* gamma = which ? g1 : g0;
  const float* beta = which ? b1 : b0;
  bf16* out = which ? out1 : out0;
  const float sc = which ? sc1 : sc0;
  const int row = blockIdx.x;
  const int t = threadIdx.x;
  float x0, x1, x2, x3;
  if constexpr (std::is_same_v<TIN, float>) {
    float4 u = *(const float4*)(in + (size_t)row * stride + t * 4);
    x0 = u.x; x1 = u.y; x2 = u.z; x3 = u.w;
  } else {
    ushort4 u = *(const ushort4*)(in + (size_t)row * stride + t * 4);
    x0 = us2f(u.x); x1 = us2f(u.y); x2 = us2f(u.z); x3 = us2f(u.w);
  }
  float s = x0 + x1 + x2 + x3;
  float s2 = x0 * x0 + x1 * x1 + x2 * x2 + x3 * x3;
#pragma unroll
  for (int m = 1; m < 64; m <<= 1) {
    s += __shfl_xor(s, m);
    s2 += __shfl_xor(s2, m);
  }
  __shared__ float red[10];
  const int w = t >> 6, lane = t & 63;
  if (lane == 0) { red[w] = s; red[4 + w] = s2; }
  __syncthreads();
  if (t == 0) {
    float S = red[0] + red[1] + red[2] + red[3];
    float S2 = red[4] + red[5] + red[6] + red[7];
    float mu = S / (float)D;
    float var = S2 / (float)D - mu * mu;
    red[8] = mu;
    red[9] = rsqrtf(var + 1e-5f);
  }
  __syncthreads();
  const float mu = red[8], rs = red[9];
  float4 g4 = *(const float4*)(gamma + t * 4);
  float4 b4 = *(const float4*)(beta + t * 4);
  uint2 o;
  o.x = pack_bf16x2(((x0 - mu) * rs * g4.x + b4.x) * sc, ((x1 - mu) * rs * g4.y + b4.y) * sc);
  o.y = pack_bf16x2(((x2 - mu) * rs * g4.z + b4.z) * sc, ((x3 - mu) * rs * g4.w + b4.w) * sc);
  *(uint2*)(out + (size_t)row * D + t * 4) = o;
}

// ---------------- all 3 weight transposes in one launch: z selects tensor ----------------
__global__ __launch_bounds__(256) void transpose3_kernel(
    const float* __restrict__ s0, bf16* __restrict__ d0,   // 1024x2048
    const float* __restrict__ s1, bf16* __restrict__ d1,   // 1024x1024
    const float* __restrict__ s2, bf16* __restrict__ d2)   // 1024x1024
{
  const int z = blockIdx.z;
  if (z > 0 && blockIdx.x >= 16) return;
  const float* in = (z == 0) ? s0 : (z == 1) ? s1 : s2;
  bf16* out = (z == 0) ? d0 : (z == 1) ? d1 : d2;
  const int R = 1024, C = (z == 0) ? 2048 : 1024;
  __shared__ float tile[64][68];
  const int r0 = blockIdx.y * 64, c0 = blockIdx.x * 64;
  const int t = threadIdx.x;
  const int lr = t >> 2, lc = (t & 3) * 16;
  const float* src = in + (size_t)(r0 + lr) * C + (c0 + lc);
#pragma unroll
  for (int i = 0; i < 4; ++i) {
    float4 u = *(const float4*)(src + i * 4);
    tile[lr][lc + i * 4 + 0] = u.x;
    tile[lr][lc + i * 4 + 1] = u.y;
    tile[lr][lc + i * 4 + 2] = u.z;
    tile[lr][lc + i * 4 + 3] = u.w;
  }
  __syncthreads();
  __align__(16) bf16 tmp[16];
#pragma unroll
  for (int j = 0; j < 16; ++j) tmp[j] = __float2bfloat16(tile[lc + j][lr]);
  bf16* dst = out + (size_t)(c0 + lr) * R + (r0 + lc);
  *(bf16x8*)dst       = *(const bf16x8*)&tmp[0];
  *(bf16x8*)(dst + 8) = *(const bf16x8*)&tmp[8];
}

// ---------------- GEMM: C(M,N) = A(M,K) @ Bt(N,K)^T (+bias), bf16 in, fp32 accum ----------------
// BK=64, single-buffered 2-barrier K-loop. XOR chunk swizzle (c ^ (row&7)) on
// 128B LDS rows -> conflict-free ds_read_b128 frags. 2x2 waves, wave tile
// (BM/2)x(BN/2). grid = (N/BN, M/BM). TMODE 1: coalesced vt store via LDS
// bounce: vt[((row>>11)*1024 + col)*2048 + (row&2047)] (BN=128, BM=64).
template <int BM, int BN, int TMODE, typename TOUT>
__global__ __launch_bounds__(256) void gemm_bt_kernel(
    const bf16* __restrict__ A, const bf16* __restrict__ Bt,
    const float* __restrict__ bias, TOUT* __restrict__ C,
    int M, int N, int K, int has_bias)
{
  constexpr int MT = BM / 32, NT = BN / 32;
  constexpr int ASL = BM / 32, BSL = BN / 32;  // 16B slots per thread (BK=64)
  __shared__ __align__(16) bf16 lA[BM * 64];
  __shared__ __align__(16) bf16 lB[BN * 64];
  constexpr int OUTSZ = (TMODE == 1) ? 128 * 68 : 1;
  __shared__ __align__(16) bf16 lOut[OUTSZ];
  const int t = threadIdx.x;
  const int w = t >> 6, lane = t & 63, l15 = lane & 15, quad = lane >> 4;
  const int wy = w >> 1, wx = w & 1;
  const bf16* Ab = A + (size_t)blockIdx.y * BM * K;
  const bf16* Bb = Bt + (size_t)blockIdx.x * BN * K;
  f32x4 acc[MT][NT] = {};

  const int sw = (quad ^ (l15 & 7)) << 3;

  for (int kc = 0; kc < K; kc += 64) {
    __syncthreads();  // prior iter's frag reads done before overwrite
#pragma unroll
    for (int i = 0; i < ASL; ++i) {
      int s = i * 256 + t;
      int row = s >> 3, c = (s & 7) ^ (row & 7);
      gl_lds16(Ab + (size_t)row * K + kc + (c << 3), lA + s * 8);
    }
#pragma unroll
    for (int i = 0; i < BSL; ++i) {
      int s = i * 256 + t;
      int row = s >> 3, c = (s & 7) ^ (row & 7);
      gl_lds16(Bb + (size_t)row * K + kc + (c << 3), lB + s * 8);
    }
    __syncthreads();  // vmcnt drained: staged data visible

    bf16x8 af[MT][2], bfr[NT][2];
#pragma unroll
    for (int mt = 0; mt < MT; ++mt) {
      const int r = wy * (BM / 2) + mt * 16 + l15;
      af[mt][0] = *(const bf16x8*)&lA[r * 64 + sw];
      af[mt][1] = *(const bf16x8*)&lA[r * 64 + (sw ^ 32)];
    }
#pragma unroll
    for (int nt = 0; nt < NT; ++nt) {
      const int r = wx * (BN / 2) + nt * 16 + l15;
      bfr[nt][0] = *(const bf16x8*)&lB[r * 64 + sw];
      bfr[nt][1] = *(const bf16x8*)&lB[r * 64 + (sw ^ 32)];
    }
#pragma unroll
    for (int mt = 0; mt < MT; ++mt)
#pragma unroll
      for (int nt = 0; nt < NT; ++nt) {
        acc[mt][nt] = MFMA_BF16(af[mt][0], bfr[nt][0], acc[mt][nt]);
        acc[mt][nt] = MFMA_BF16(af[mt][1], bfr[nt][1], acc[mt][nt]);
      }
  }

  if constexpr (TMODE == 1) {
    // acc: row n = wy*32+mt*16+quad*4+r, col d = wx*64+nt*16+l15 -> lOut[d][n]
    __syncthreads();
#pragma unroll
    for (int mt = 0; mt < MT; ++mt)
#pragma unroll
      for (int nt = 0; nt < NT; ++nt) {
        const int d = wx * (BN / 2) + nt * 16 + l15;
        const int n = wy * 32 + mt * 16 + quad * 4;
        uint2 pk;
        pk.x = pack_bf16x2(acc[mt][nt][0], acc[mt][nt][1]);
        pk.y = pack_bf16x2(acc[mt][nt][2], acc[mt][nt][3]);
        *(uint2*)&lOut[d * 68 + n] = pk;
      }
    __syncthreads();
    const int row0 = blockIdx.y * BM;
    const int bidx = row0 >> 11, n0 = row0 & 2047;
    const int col0 = blockIdx.x * BN;
    const int d = t >> 1, half = (t & 1) * 32;
    const bf16* srcp = &lOut[d * 68 + half];
    __align__(16) bf16 tmp[32];
#pragma unroll
    for (int j = 0; j < 8; ++j)
      *(uint2*)&tmp[j * 4] = *(const uint2*)(srcp + j * 4);
    bf16* g = (bf16*)C + ((size_t)(bidx << 10) + col0 + d) * 2048 + n0 + half;
#pragma unroll
    for (int j = 0; j < 4; ++j)
      *(bf16x8*)(g + j * 8) = *(const bf16x8*)&tmp[j * 8];
  } else {
    const int row_base = blockIdx.y * BM + wy * (BM / 2);
    const int col_base = blockIdx.x * BN + wx * (BN / 2);
#pragma unroll
    for (int mt = 0; mt < MT; ++mt)
#pragma unroll
      for (int nt = 0; nt < NT; ++nt) {
        const int col = col_base + nt * 16 + l15;
        const float bb = has_bias ? bias[col] : 0.0f;
#pragma unroll
        for (int r = 0; r < 4; ++r) {
          const int row = row_base + mt * 16 + quad * 4 + r;
          float v = acc[mt][nt][r] + bb;
          if constexpr (std::is_same_v<TOUT, bf16>)
            C[(size_t)row * N + col] = __float2bfloat16(v);
          else
            C[(size_t)row * N + col] = v;
        }
      }
  }
}

// ---------------- Flash attention (R6 design — measured best) ----------------
__global__ __launch_bounds__(256) void flash_kernel(
    const bf16* __restrict__ Q, const bf16* __restrict__ Km,
    const bf16* __restrict__ Vt, bf16* __restrict__ O)
{
  __shared__ __align__(16) bf16 smem[9216 + 8192 + 8192 + 8192];
  bf16* lP = smem;                         // 4 waves x 32x72
  bf16* lQ = smem + 9216;                  // 128x64
  bf16* lKb = smem + 9216 + 8192;          // 2 x 64x64
  bf16* lVb = smem + 9216 + 8192 + 8192;   // 2 x 64x64
  const int t = threadIdx.x;
  const int w = t >> 6, lane = t & 63, l15 = lane & 15, quad = lane >> 4;
  const int qt = blockIdx.x, bh = blockIdx.y;
  const int b = bh >> 4, h = bh & 15;
  const int qrow0 = b * 2048 + qt * 128;
  const bf16* qbase = Q + (size_t)qrow0 * 1024 + h * 64;
  const bf16* kbase = Km + ((size_t)(b * 2048)) * 1024 + h * 64;
  const bf16* vbase = Vt + ((size_t)(b * 1024 + h * 64)) * 2048;
  bf16* lPm = lP + w * (32 * 72);

  const int sr0 = t >> 3, sc0 = ((t & 7) ^ (sr0 & 7)) << 3;
  const int sr1 = (256 + t) >> 3, sc1 = (((256 + t) & 7) ^ (sr1 & 7)) << 3;
  const bf16* kp0 = kbase + sr0 * 1024 + sc0;
  const bf16* kp1 = kbase + sr1 * 1024 + sc1;
  const bf16* vp0 = vbase + sr0 * 2048 + sc0;
  const bf16* vp1 = vbase + sr1 * 2048 + sc1;

  // prologue: stage Q (4) + K/V tile 0 (4)
#pragma unroll
  for (int i = 0; i < 4; ++i) {
    int s = i * 256 + t;
    int row = s >> 3, c = (s & 7) ^ (row & 7);
    gl_lds16(qbase + (size_t)row * 1024 + (c << 3), lQ + s * 8);
  }
  gl_lds16(kp0, lKb + t * 8);
  gl_lds16(kp1, lKb + (256 + t) * 8);
  gl_lds16(vp0, lVb + t * 8);
  gl_lds16(vp1, lVb + (256 + t) * 8);
  asm volatile("s_waitcnt vmcnt(4)" ::: "memory");  // Q done (FIFO), tile0 in flight
  __builtin_amdgcn_s_barrier();

  const int sw = (quad ^ (l15 & 7)) << 3;
  bf16x8 qf[2][2];
#pragma unroll
  for (int mset = 0; mset < 2; ++mset) {
    const int row = w * 32 + mset * 16 + l15;
    qf[mset][0] = *(const bf16x8*)&lQ[row * 64 + sw];
    qf[mset][1] = *(const bf16x8*)&lQ[row * 64 + (sw ^ 32)];
  }

  f32x4 o_acc[4][2] = {};   // [dt][mset]: O^T row d = dt*16+quad*4+r, col m = mset*16+l15
  f32x4 l_vec[2] = {};      // in-lane partial row sums

  for (int kt = 0; kt < 32; ++kt) {
    const int cur = kt & 1;
    bf16* lK = lKb + cur * 4096;
    bf16* lV = lVb + cur * 4096;
    bf16* lKn = lKb + (cur ^ 1) * 4096;
    bf16* lVn = lVb + (cur ^ 1) * 4096;

    __builtin_amdgcn_s_barrier();  // all waves done reading buf cur^1
    {
      const int ktn = (kt + 1) & 31;  // wrap: restage tile 0 into dead buf
      const int ko = ktn << 16;       // ktn*64 rows * 1024
      const int vo = ktn << 6;        // ktn*64 cols
      gl_lds16(kp0 + ko, lKn + t * 8);
      gl_lds16(kp1 + ko, lKn + (256 + t) * 8);
      gl_lds16(vp0 + vo, lVn + t * 8);
      gl_lds16(vp1 + vo, lVn + (256 + t) * 8);
    }
    asm volatile("s_waitcnt vmcnt(4)" ::: "memory");
    __builtin_amdgcn_s_barrier();

    bf16x8 kf[4][2];
#pragma unroll
    for (int nt = 0; nt < 4; ++nt) {
      kf[nt][0] = *(const bf16x8*)&lK[(nt * 16 + l15) * 64 + sw];
      kf[nt][1] = *(const bf16x8*)&lK[(nt * 16 + l15) * 64 + (sw ^ 32)];
    }

    // S^T (log2-domain) + v_exp + truncating pack + P write (wave-private)
#pragma unroll
    for (int mset = 0; mset < 2; ++mset) {
#pragma unroll
      for (int nt = 0; nt < 4; ++nt) {
        f32x4 z = {};
        z = MFMA_BF16(kf[nt][0], qf[mset][0], z);
        z = MFMA_BF16(kf[nt][1], qf[mset][1], z);
        f32x4 p;
#pragma unroll
        for (int r = 0; r < 4; ++r) p[r] = __builtin_amdgcn_exp2f(z[r]);
        l_vec[mset] += p;
        uint2 pk;
        pk.x = pack_bf16x2_trunc(p[0], p[1]);
        pk.y = pack_bf16x2_trunc(p[2], p[3]);
        *(uint2*)&lPm[(mset * 16 + l15) * 72 + nt * 16 + quad * 4] = pk;
      }
    }

    bf16x8 vf[4][2];
#pragma unroll
    for (int dt = 0; dt < 4; ++dt) {
      vf[dt][0] = *(const bf16x8*)&lV[(dt * 16 + l15) * 64 + sw];
      vf[dt][1] = *(const bf16x8*)&lV[(dt * 16 + l15) * 64 + (sw ^ 32)];
    }
    asm volatile("s_waitcnt lgkmcnt(0)" ::: "memory");  // P writes landed

#pragma unroll
    for (int mset = 0; mset < 2; ++mset) {
      const bf16* pr = &lPm[(mset * 16 + l15) * 72 + quad * 8];
      bf16x8 pf0 = *(const bf16x8*)pr;
      bf16x8 pf1 = *(const bf16x8*)(pr + 32);
#pragma unroll
      for (int dt = 0; dt < 4; ++dt) {
        o_acc[dt][mset] = MFMA_BF16(vf[dt][0], pf0, o_acc[dt][mset]);
        o_acc[dt][mset] = MFMA_BF16(vf[dt][1], pf1, o_acc[dt][mset]);
      }
    }
  }

  // epilogue: cross-quad row sums + divide + store O^T fragments
#pragma unroll
  for (int mset = 0; mset < 2; ++mset) {
    float tsum = l_vec[mset][0] + l_vec[mset][1] + l_vec[mset][2] + l_vec[mset][3];
    tsum += __shfl_xor(tsum, 16);
    tsum += __shfl_xor(tsum, 32);
    const float inv = 1.0f / tsum;
    const int m = qrow0 + w * 32 + mset * 16 + l15;
#pragma unroll
    for (int dt = 0; dt < 4; ++dt) {
      uint2 ok;
      ok.x = pack_bf16x2(o_acc[dt][mset][0] * inv, o_acc[dt][mset][1] * inv);
      ok.y = pack_bf16x2(o_acc[dt][mset][2] * inv, o_acc[dt][mset][3] * inv);
      *(uint2*)&O[(size_t)m * 1024 + h * 64 + dt * 16 + quad * 4] = ok;
    }
  }
}

extern "C" void kernel_launch(void* const* d_in, const int* in_sizes, int n_in,
                              void* d_out, int out_size, void* d_ws, size_t ws_size,
                              hipStream_t stream)
{
  (void)in_sizes; (void)n_in; (void)out_size; (void)ws_size;
  const float* keys   = (const float*)d_in[0];
  const float* values = (const float*)d_in[1];
  const float* qk_g   = (const float*)d_in[2];
  const float* qk_b   = (const float*)d_in[3];
  const float* val_g  = (const float*)d_in[4];
  const float* val_b  = (const float*)d_in[5];
  const float* key_g  = (const float*)d_in[6];
  const float* key_b  = (const float*)d_in[7];
  const float* qry_g  = (const float*)d_in[8];
  const float* qry_b  = (const float*)d_in[9];
  const float* w_qk   = (const float*)d_in[10];
  const float* w_v    = (const float*)d_in[11];
  const float* w_out  = (const float*)d_in[12];
  const float* b_out  = (const float*)d_in[13];
  float* out = (float*)d_out;

  const float CEXP = 0.03125f * 1.44269504f;  // ID^-0.5 * log2(e), folded into q-LN

  char* ws = (char*)d_ws;
  const size_t MB = 1024 * 1024;
  bf16* keys_ln   = (bf16*)(ws + 0);        // 8MB
  bf16* values_ln = (bf16*)(ws + 8 * MB);   // 8MB
  bf16* qk        = (bf16*)(ws + 16 * MB);  // 16MB
  bf16* attn      = (bf16*)(ws + 16 * MB);  // 8MB (qk dead)
  bf16* vt        = (bf16*)(ws + 24 * MB);  // 8MB
  bf16* qln       = (bf16*)(ws + 32 * MB);  // 8MB
  bf16* kln       = (bf16*)(ws + 40 * MB);  // 8MB
  bf16* wqkT      = (bf16*)(ws + 48 * MB);  // 4MB
  bf16* wvT       = (bf16*)(ws + 52 * MB);  // 2MB
  bf16* woutT     = (bf16*)(ws + 54 * MB);  // 2MB

  // L1: both input layernorms
  ln2_kernel<float><<<dim3(4096, 2), 256, 0, stream>>>(
      keys, values, 1024, qk_g, qk_b, val_g, val_b, keys_ln, values_ln, 1024, 1.0f, 1.0f);
  // L2: all weight transposes
  transpose3_kernel<<<dim3(32, 16, 3), 256, 0, stream>>>(w_qk, wqkT, w_v, wvT, w_out, woutT);
  // L3: qk = keys_ln @ w_qk (4096x2048), 64x128xBK64 -> 1024 blocks
  gemm_bt_kernel<64, 128, 0, bf16><<<dim3(16, 64), 256, 0, stream>>>(keys_ln, wqkT, nullptr, qk, 4096, 2048, 1024, 0);
  // L4: q/k layernorms; qln pre-scaled by CEXP
  ln2_kernel<bf16><<<dim3(4096, 2), 256, 0, stream>>>(
      qk, qk + 1024, 2048, qry_g, qry_b, key_g, key_b, qln, kln, 1024, CEXP, 1.0f);
  // L5: v = values_ln @ w_v -> vt (transposed store), 64x128xBK64 -> 512 blocks
  gemm_bt_kernel<64, 128, 1, bf16><<<dim3(8, 64), 256, 0, stream>>>(values_ln, wvT, nullptr, vt, 4096, 1024, 1024, 0);
  // L6: flash attention -> attn
  flash_kernel<<<dim3(16, 32), 256, 0, stream>>>(qln, kln, vt, attn);
  // L7: out = attn @ w_out + b_out (fp32 out), 64x128xBK64 -> 512 blocks
  gemm_bt_kernel<64, 128, 0, float><<<dim3(8, 64), 256, 0, stream>>>(attn, woutT, b_out, out, 4096, 1024, 1024, 1);
}